// Round 1
// baseline (3022.758 us; speedup 1.0000x reference)
//
#include <hip/hip_runtime.h>
#include <cstddef>
#include <cstdint>

// Problem constants (from reference setup_inputs): B=8, K=64, H=W=384
#define HW 147456
#define BATCH 8
#define KROW 64
#define NBLK_PER_B 128
#define CHUNK 1152   // HW / NBLK_PER_B
#define PSUB 32      // pixels per LDS tile
#define NT 36        // CHUNK / PSUB

// Workspace layout (float offsets). Total ~4.29M floats ~= 17.2 MB.
#define PART_CROSS 0
#define PART_S     (1024 * 4096)            // 4194304
#define CROSS_RED  (PART_S + 1024 * 64)     // 4259840
#define S_RED      (CROSS_RED + 8 * 4096)   // 4292608
#define BTOT       (S_RED + 8 * 64)         // 4293120

// ---------------------------------------------------------------------------
// K1: per (batch, pixel-chunk) block: partial cross[64][64] and partial S[64]
// ---------------------------------------------------------------------------
__global__ __launch_bounds__(256, 4)
void k1_cross(const float* __restrict__ preds, const float* __restrict__ targets,
              float* __restrict__ ws) {
    // smem: X tiles [0,4096) = 2 bufs x 32 px x 64 rows ; T tiles [4096,8192)
    __shared__ float smem[8192];
    const int t   = threadIdx.x;
    const int bid = blockIdx.x;
    const int b   = bid >> 7;
    const int c   = bid & (NBLK_PER_B - 1);
    const int px0 = c * CHUNK;

    const int w  = t >> 6;   // wave 0..3
    const int l  = t & 63;
    const int ti = l >> 3;   // row-tile 0..7
    const int tj = l & 7;    // col-tile 0..7

    // staging mapping: threads <128 stage X (and softplus), >=128 stage T
    const bool matX = (t < 128);
    const int  sthr = t & 127;
    const int  r    = sthr >> 1;   // row 0..63
    const int  half = sthr & 1;    // which 16-px half
    const float* srcRow = (matX ? preds : targets)
        + (size_t)(b * KROW + r) * HW + px0 + 16 * half;
    const int ldsBase = matX ? 0 : 4096;

    float acc[8][8];
#pragma unroll
    for (int a = 0; a < 8; ++a)
#pragma unroll
        for (int q = 0; q < 8; ++q) acc[a][q] = 0.f;

    float sAcc = 0.f;
    float4 ld[4];

    // stage tile 0 into buf 0
    {
        const float4* g = (const float4*)srcRow;
#pragma unroll
        for (int i = 0; i < 4; ++i) ld[i] = g[i];
#pragma unroll
        for (int i = 0; i < 4; ++i) {
            float v[4] = {ld[i].x, ld[i].y, ld[i].z, ld[i].w};
#pragma unroll
            for (int k = 0; k < 4; ++k) {
                if (matX) {
                    const float x = v[k];
                    sAcc += fmaxf(x, 0.f) + log1pf(expf(-fabsf(x)));
                }
                smem[ldsBase + (16 * half + 4 * i + k) * 64 + r] = v[k];
            }
        }
    }
    __syncthreads();

    for (int tile = 0; tile < NT; ++tile) {
        const int  buf  = tile & 1;
        const bool more = (tile + 1 < NT);
        if (more) {  // issue next tile's global loads before compute (latency hide)
            const float4* g = (const float4*)(srcRow + (tile + 1) * PSUB);
#pragma unroll
            for (int i = 0; i < 4; ++i) ld[i] = g[i];
        }
        // compute: wave w handles pixels [8w, 8w+8) of this tile
        {
            const float* xs = &smem[buf * 2048 + (w * 8) * 64 + ti * 8];
            const float* ts = &smem[4096 + buf * 2048 + (w * 8) * 64 + tj * 8];
#pragma unroll
            for (int p = 0; p < 8; ++p) {
                const float4* x4 = (const float4*)(xs + p * 64);
                const float4* t4 = (const float4*)(ts + p * 64);
                const float4 xa = x4[0], xb = x4[1];
                const float4 ta = t4[0], tb = t4[1];
                const float xv[8] = {xa.x, xa.y, xa.z, xa.w, xb.x, xb.y, xb.z, xb.w};
                const float tv[8] = {ta.x, ta.y, ta.z, ta.w, tb.x, tb.y, tb.z, tb.w};
#pragma unroll
                for (int a = 0; a < 8; ++a)
#pragma unroll
                    for (int q = 0; q < 8; ++q)
                        acc[a][q] += xv[a] * tv[q];
            }
        }
        if (more) {
            __syncthreads();   // everyone done reading buf^1 (>=2 barriers ago) + this buf
            const int nbuf = buf ^ 1;
#pragma unroll
            for (int i = 0; i < 4; ++i) {
                float v[4] = {ld[i].x, ld[i].y, ld[i].z, ld[i].w};
#pragma unroll
                for (int k = 0; k < 4; ++k) {
                    if (matX) {
                        const float x = v[k];
                        sAcc += fmaxf(x, 0.f) + log1pf(expf(-fabsf(x)));
                    }
                    smem[ldsBase + nbuf * 2048 + (16 * half + 4 * i + k) * 64 + r] = v[k];
                }
            }
            __syncthreads();
        }
    }

    // cross-wave reduction of acc into smem[0,4096)
    __syncthreads();
    for (int ww = 0; ww < 4; ++ww) {
        if (w == ww) {
#pragma unroll
            for (int a = 0; a < 8; ++a)
#pragma unroll
                for (int q = 0; q < 8; ++q) {
                    const int idx = (ti * 8 + a) * 64 + tj * 8 + q;
                    if (ww == 0) smem[idx] = acc[a][q];
                    else         smem[idx] += acc[a][q];
                }
        }
        __syncthreads();
    }
    // write partial cross (coalesced float4)
    {
        float4* dst = (float4*)(ws + (size_t)PART_CROSS + (size_t)bid * 4096);
        const float4* s4 = (const float4*)smem;
#pragma unroll
        for (int k = 0; k < 4; ++k) dst[t + 256 * k] = s4[t + 256 * k];
    }
    // partial S: pair-reduce the two threads sharing a row
    {
        const float s2 = sAcc + __shfl_xor(sAcc, 1);
        if (matX && ((t & 1) == 0))
            ws[PART_S + (size_t)bid * 64 + r] = s2;
    }
}

// ---------------------------------------------------------------------------
// K2: reduce 128 partials per batch -> cross_red[8][4096], S_red[8][64]
// ---------------------------------------------------------------------------
__global__ __launch_bounds__(256)
void k2_reduce(float* __restrict__ ws) {
    const int t = threadIdx.x;
    const int g = blockIdx.x;   // 0..16
    const int b = blockIdx.y;   // 0..7
    if (g < 16) {
        const int e = g * 256 + t;
        const float* p = ws + (size_t)PART_CROSS + (size_t)b * NBLK_PER_B * 4096 + e;
        float s = 0.f;
#pragma unroll 8
        for (int c = 0; c < NBLK_PER_B; ++c) s += p[(size_t)c * 4096];
        ws[CROSS_RED + (size_t)b * 4096 + e] = s;
    } else if (t < 64) {
        const float* p = ws + (size_t)PART_S + (size_t)b * NBLK_PER_B * 64 + t;
        float s = 0.f;
#pragma unroll 8
        for (int c = 0; c < NBLK_PER_B; ++c) s += p[c * 64];
        ws[S_RED + b * 64 + t] = s;
    }
}

// ---------------------------------------------------------------------------
// K3: per-batch sinkhorn (exact reference replica) + <P, C>
// thread mapping: row phase: i = t>>2 owns row i, 4 threads x 16 cols
//                 col phase: j = t>>2 owns col j, 4 threads x 16 rows
// ---------------------------------------------------------------------------
__global__ __launch_bounds__(256)
void k3_sinkhorn(float* __restrict__ ws) {
    __shared__ float Q[64 * 65];
    __shared__ float wred[4];
    const int t  = threadIdx.x;
    const int b  = blockIdx.x;
    const int i  = t >> 2;
    const int qq = t & 3;
    const float* cr = ws + CROSS_RED + (size_t)b * 4096;
    const float S_i = ws[S_RED + b * 64 + i];

    // Q0 = -cost = cross - S_i ; row max
    float q0[16];
    float m = -3.4e38f;
#pragma unroll
    for (int n = 0; n < 16; ++n) {
        const float v = cr[i * 64 + qq * 16 + n] - S_i;
        q0[n] = v;
        m = fmaxf(m, v);
    }
    m = fmaxf(m, __shfl_xor(m, 1));
    m = fmaxf(m, __shfl_xor(m, 2));
    // exp(clip((q-m)/REG, -10, 10)) ; row normalize with +EPS
    float rs = 0.f;
#pragma unroll
    for (int n = 0; n < 16; ++n) {
        const float e = expf(fminf(fmaxf((q0[n] - m) / 0.1f, -10.f), 10.f));
        q0[n] = e;
        rs += e;
    }
    rs += __shfl_xor(rs, 1);
    rs += __shfl_xor(rs, 2);
    const float inv = 1.f / (rs + 1e-8f);
#pragma unroll
    for (int n = 0; n < 16; ++n) Q[i * 65 + qq * 16 + n] = q0[n] * inv;
    __syncthreads();

    const int jc  = t >> 2;
    const int i16 = (t & 3) * 16;
    for (int it = 0; it < 20; ++it) {
        // row rescale: Q *= r / (rowsum + EPS), r = 1/64
        float u = 0.f;
#pragma unroll
        for (int n = 0; n < 16; ++n) u += Q[i * 65 + qq * 16 + n];
        u += __shfl_xor(u, 1);
        u += __shfl_xor(u, 2);
        const float f = 0.015625f / (u + 1e-8f);
#pragma unroll
        for (int n = 0; n < 16; ++n) Q[i * 65 + qq * 16 + n] *= f;
        __syncthreads();
        // col rescale: Q *= c / (colsum + EPS), c = 1/64
        float vv = 0.f;
#pragma unroll
        for (int n = 0; n < 16; ++n) vv += Q[(i16 + n) * 65 + jc];
        vv += __shfl_xor(vv, 1);
        vv += __shfl_xor(vv, 2);
        const float g2 = 0.015625f / (vv + 1e-8f);
#pragma unroll
        for (int n = 0; n < 16; ++n) Q[(i16 + n) * 65 + jc] *= g2;
        __syncthreads();
    }

    // total_b = sum(P * cost), cost = S_i - cross
    float tot = 0.f;
#pragma unroll
    for (int n = 0; n < 16; ++n) {
        const int j = qq * 16 + n;
        const float cost = S_i - cr[i * 64 + j];
        tot += Q[i * 65 + j] * cost;
    }
#pragma unroll
    for (int s = 1; s < 64; s <<= 1) tot += __shfl_xor(tot, s);
    if ((t & 63) == 0) wred[t >> 6] = tot;
    __syncthreads();
    if (t == 0) ws[BTOT + b] = wred[0] + wred[1] + wred[2] + wred[3];
}

// ---------------------------------------------------------------------------
// K4: final scalar
// ---------------------------------------------------------------------------
__global__ void k4_final(const float* __restrict__ ws, float* __restrict__ out) {
    const int t = threadIdx.x;
    float v = (t < 8) ? ws[BTOT + t] : 0.f;
    v += __shfl_xor(v, 1);
    v += __shfl_xor(v, 2);
    v += __shfl_xor(v, 4);
    if (t == 0) out[0] = v / (float)HW;
}

extern "C" void kernel_launch(void* const* d_in, const int* in_sizes, int n_in,
                              void* d_out, int out_size, void* d_ws, size_t ws_size,
                              hipStream_t stream) {
    const float* preds   = (const float*)d_in[0];
    const float* targets = (const float*)d_in[1];
    float* ws  = (float*)d_ws;
    float* out = (float*)d_out;

    hipLaunchKernelGGL(k1_cross,    dim3(1024),   dim3(256), 0, stream, preds, targets, ws);
    hipLaunchKernelGGL(k2_reduce,   dim3(17, 8),  dim3(256), 0, stream, ws);
    hipLaunchKernelGGL(k3_sinkhorn, dim3(8),      dim3(256), 0, stream, ws);
    hipLaunchKernelGGL(k4_final,    dim3(1),      dim3(64),  0, stream, ws, out);
}

// Round 2
// 941.797 us; speedup vs baseline: 3.2096x; 3.2096x over previous
//
#include <hip/hip_runtime.h>
#include <cstddef>
#include <cstdint>

// Problem constants (from reference setup_inputs): B=8, K=64, H=W=384
#define HW 147456
#define BATCH 8
#define KROW 64
#define NBLK_PER_B 128
#define CHUNK 1152   // HW / NBLK_PER_B
#define PSUB 32      // pixels per LDS tile
#define NT 36        // CHUNK / PSUB

// Workspace layout (float offsets). Total ~4.29M floats ~= 17.2 MB.
#define PART_CROSS 0
#define PART_S     (1024 * 4096)            // 4194304
#define CROSS_RED  (PART_S + 1024 * 64)     // 4259840
#define S_RED      (CROSS_RED + 8 * 4096)   // 4292608
#define BTOT       (S_RED + 8 * 64)         // 4293120

// ---------------------------------------------------------------------------
// K1: per (batch, pixel-chunk) block: partial cross[64][64] and partial S[64]
// Wave w owns output quadrant (w>>1, w&1); each thread a 4x4 register tile.
// Per-thread state: 16 acc + 8 frag + 16 staging = no spill (vs R1's 64-acc
// tile that spilled at VGPR_Count=64 and produced 6 GB of scratch writes).
// ---------------------------------------------------------------------------
__global__ __launch_bounds__(256)
void k1_cross(const float* __restrict__ preds, const float* __restrict__ targets,
              float* __restrict__ ws) {
    // smem: X tiles [0,4096) = 2 bufs x 32 px x 64 rows ; T tiles [4096,8192)
    __shared__ float smem[8192];
    const int t   = threadIdx.x;
    const int bid = blockIdx.x;
    const int b   = bid >> 7;
    const int c   = bid & (NBLK_PER_B - 1);
    const int px0 = c * CHUNK;

    const int w  = t >> 6;            // wave 0..3
    const int l  = t & 63;
    const int wr = (w >> 1) * 32;     // quadrant row base
    const int wc = (w & 1) * 32;      // quadrant col base
    const int li = (l >> 3) * 4;      // sub-row 0,4,..28
    const int lj = (l & 7) * 4;       // sub-col 0,4,..28

    // staging mapping: threads <128 stage X (and softplus), >=128 stage T
    const bool matX = (t < 128);
    const int  sthr = t & 127;
    const int  r    = sthr >> 1;   // row 0..63
    const int  half = sthr & 1;    // which 16-px half
    const float* srcRow = (matX ? preds : targets)
        + (size_t)(b * KROW + r) * HW + px0 + 16 * half;
    const int ldsBase = matX ? 0 : 4096;

    float acc[4][4];
#pragma unroll
    for (int a = 0; a < 4; ++a)
#pragma unroll
        for (int q = 0; q < 4; ++q) acc[a][q] = 0.f;

    float sAcc = 0.f;
    float4 ld[4];

    // stage tile 0 into buf 0
    {
        const float4* g = (const float4*)srcRow;
#pragma unroll
        for (int i = 0; i < 4; ++i) ld[i] = g[i];
#pragma unroll
        for (int i = 0; i < 4; ++i) {
            float v[4] = {ld[i].x, ld[i].y, ld[i].z, ld[i].w};
#pragma unroll
            for (int k = 0; k < 4; ++k) {
                if (matX) {
                    const float x = v[k];
                    sAcc += fmaxf(x, 0.f) + log1pf(expf(-fabsf(x)));
                }
                smem[ldsBase + (16 * half + 4 * i + k) * 64 + r] = v[k];
            }
        }
    }
    __syncthreads();

    for (int tile = 0; tile < NT; ++tile) {
        const int  buf  = tile & 1;
        const bool more = (tile + 1 < NT);
        if (more) {  // issue next tile's global loads before compute (latency hide)
            const float4* g = (const float4*)(srcRow + (tile + 1) * PSUB);
#pragma unroll
            for (int i = 0; i < 4; ++i) ld[i] = g[i];
        }
        // compute: this wave's 32x32 quadrant over all 32 pixels of the tile
        {
            const float* xs = &smem[buf * 2048 + wr + li];
            const float* ts = &smem[4096 + buf * 2048 + wc + lj];
#pragma unroll 4
            for (int p = 0; p < PSUB; ++p) {
                const float4 xv = *(const float4*)(xs + p * 64);
                const float4 tv = *(const float4*)(ts + p * 64);
                const float xa[4] = {xv.x, xv.y, xv.z, xv.w};
                const float ta[4] = {tv.x, tv.y, tv.z, tv.w};
#pragma unroll
                for (int a = 0; a < 4; ++a)
#pragma unroll
                    for (int q = 0; q < 4; ++q)
                        acc[a][q] += xa[a] * ta[q];
            }
        }
        if (more) {
            __syncthreads();   // everyone done reading this buf's sibling
            const int nbuf = buf ^ 1;
#pragma unroll
            for (int i = 0; i < 4; ++i) {
                float v[4] = {ld[i].x, ld[i].y, ld[i].z, ld[i].w};
#pragma unroll
                for (int k = 0; k < 4; ++k) {
                    if (matX) {
                        const float x = v[k];
                        sAcc += fmaxf(x, 0.f) + log1pf(expf(-fabsf(x)));
                    }
                    smem[ldsBase + nbuf * 2048 + (16 * half + 4 * i + k) * 64 + r] = v[k];
                }
            }
            __syncthreads();
        }
    }

    // direct partial-cross write: quadrants are disjoint, no LDS reduction
    {
        float* dst = ws + (size_t)PART_CROSS + (size_t)bid * 4096;
#pragma unroll
        for (int a = 0; a < 4; ++a) {
            float4 v = make_float4(acc[a][0], acc[a][1], acc[a][2], acc[a][3]);
            *(float4*)(dst + (wr + li + a) * 64 + wc + lj) = v;
        }
    }
    // partial S: pair-reduce the two threads sharing a row
    {
        const float s2 = sAcc + __shfl_xor(sAcc, 1);
        if (matX && ((t & 1) == 0))
            ws[PART_S + (size_t)bid * 64 + r] = s2;
    }
}

// ---------------------------------------------------------------------------
// K2: reduce 128 partials per batch -> cross_red[8][4096], S_red[8][64]
// ---------------------------------------------------------------------------
__global__ __launch_bounds__(256)
void k2_reduce(float* __restrict__ ws) {
    const int t = threadIdx.x;
    const int g = blockIdx.x;   // 0..16
    const int b = blockIdx.y;   // 0..7
    if (g < 16) {
        const int e = g * 256 + t;
        const float* p = ws + (size_t)PART_CROSS + (size_t)b * NBLK_PER_B * 4096 + e;
        float s = 0.f;
#pragma unroll 8
        for (int c = 0; c < NBLK_PER_B; ++c) s += p[(size_t)c * 4096];
        ws[CROSS_RED + (size_t)b * 4096 + e] = s;
    } else if (t < 64) {
        const float* p = ws + (size_t)PART_S + (size_t)b * NBLK_PER_B * 64 + t;
        float s = 0.f;
#pragma unroll 8
        for (int c = 0; c < NBLK_PER_B; ++c) s += p[c * 64];
        ws[S_RED + b * 64 + t] = s;
    }
}

// ---------------------------------------------------------------------------
// K3: per-batch sinkhorn (exact reference replica) + <P, C>
// ---------------------------------------------------------------------------
__global__ __launch_bounds__(256)
void k3_sinkhorn(float* __restrict__ ws) {
    __shared__ float Q[64 * 65];
    __shared__ float wred[4];
    const int t  = threadIdx.x;
    const int b  = blockIdx.x;
    const int i  = t >> 2;
    const int qq = t & 3;
    const float* cr = ws + CROSS_RED + (size_t)b * 4096;
    const float S_i = ws[S_RED + b * 64 + i];

    // Q0 = -cost = cross - S_i ; row max
    float q0[16];
    float m = -3.4e38f;
#pragma unroll
    for (int n = 0; n < 16; ++n) {
        const float v = cr[i * 64 + qq * 16 + n] - S_i;
        q0[n] = v;
        m = fmaxf(m, v);
    }
    m = fmaxf(m, __shfl_xor(m, 1));
    m = fmaxf(m, __shfl_xor(m, 2));
    // exp(clip((q-m)/REG, -10, 10)) ; row normalize with +EPS
    float rs = 0.f;
#pragma unroll
    for (int n = 0; n < 16; ++n) {
        const float e = expf(fminf(fmaxf((q0[n] - m) / 0.1f, -10.f), 10.f));
        q0[n] = e;
        rs += e;
    }
    rs += __shfl_xor(rs, 1);
    rs += __shfl_xor(rs, 2);
    const float inv = 1.f / (rs + 1e-8f);
#pragma unroll
    for (int n = 0; n < 16; ++n) Q[i * 65 + qq * 16 + n] = q0[n] * inv;
    __syncthreads();

    const int jc  = t >> 2;
    const int i16 = (t & 3) * 16;
    for (int it = 0; it < 20; ++it) {
        // row rescale: Q *= r / (rowsum + EPS), r = 1/64
        float u = 0.f;
#pragma unroll
        for (int n = 0; n < 16; ++n) u += Q[i * 65 + qq * 16 + n];
        u += __shfl_xor(u, 1);
        u += __shfl_xor(u, 2);
        const float f = 0.015625f / (u + 1e-8f);
#pragma unroll
        for (int n = 0; n < 16; ++n) Q[i * 65 + qq * 16 + n] *= f;
        __syncthreads();
        // col rescale: Q *= c / (colsum + EPS), c = 1/64
        float vv = 0.f;
#pragma unroll
        for (int n = 0; n < 16; ++n) vv += Q[(i16 + n) * 65 + jc];
        vv += __shfl_xor(vv, 1);
        vv += __shfl_xor(vv, 2);
        const float g2 = 0.015625f / (vv + 1e-8f);
#pragma unroll
        for (int n = 0; n < 16; ++n) Q[(i16 + n) * 65 + jc] *= g2;
        __syncthreads();
    }

    // total_b = sum(P * cost), cost = S_i - cross
    float tot = 0.f;
#pragma unroll
    for (int n = 0; n < 16; ++n) {
        const int j = qq * 16 + n;
        const float cost = S_i - cr[i * 64 + j];
        tot += Q[i * 65 + j] * cost;
    }
#pragma unroll
    for (int s = 1; s < 64; s <<= 1) tot += __shfl_xor(tot, s);
    if ((t & 63) == 0) wred[t >> 6] = tot;
    __syncthreads();
    if (t == 0) ws[BTOT + b] = wred[0] + wred[1] + wred[2] + wred[3];
}

// ---------------------------------------------------------------------------
// K4: final scalar
// ---------------------------------------------------------------------------
__global__ void k4_final(const float* __restrict__ ws, float* __restrict__ out) {
    const int t = threadIdx.x;
    float v = (t < 8) ? ws[BTOT + t] : 0.f;
    v += __shfl_xor(v, 1);
    v += __shfl_xor(v, 2);
    v += __shfl_xor(v, 4);
    if (t == 0) out[0] = v / (float)HW;
}

extern "C" void kernel_launch(void* const* d_in, const int* in_sizes, int n_in,
                              void* d_out, int out_size, void* d_ws, size_t ws_size,
                              hipStream_t stream) {
    const float* preds   = (const float*)d_in[0];
    const float* targets = (const float*)d_in[1];
    float* ws  = (float*)d_ws;
    float* out = (float*)d_out;

    hipLaunchKernelGGL(k1_cross,    dim3(1024),   dim3(256), 0, stream, preds, targets, ws);
    hipLaunchKernelGGL(k2_reduce,   dim3(17, 8),  dim3(256), 0, stream, ws);
    hipLaunchKernelGGL(k3_sinkhorn, dim3(8),      dim3(256), 0, stream, ws);
    hipLaunchKernelGGL(k4_final,    dim3(1),      dim3(64),  0, stream, ws, out);
}